// Round 4
// baseline (1073.996 us; speedup 1.0000x reference)
//
#include <hip/hip_runtime.h>

typedef __bf16 bf16;
typedef bf16 bf16x8 __attribute__((ext_vector_type(8)));
typedef float f32x4 __attribute__((ext_vector_type(4)));

#define NUM_MOLS 2000
#define APM 50
#define NA (NUM_MOLS*APM+1)      // 100001
#define NB (2*NUM_MOLS*APM+1)    // 200001
#define MAX_NB 6
#define AF 133
#define BFD 147
#define H 300
#define HP 320
#define KIP 192                  // padded BOND_FDIM (3 x 64)
#define KO 448                   // padded concat dim: 133 + 3 pad + 300 + 12 pad
#define AOFF 136                 // a_message column offset inside cat
#define BM 64

// ---------------- weight prep (pad + transpose to [N][K] bf16) ----------------
__global__ void k_prep_wi(const float* __restrict__ Wi, bf16* __restrict__ Wt){ // [HP][KIP]
    int i = blockIdx.x*256 + threadIdx.x; if (i >= HP*KIP) return;
    int n = i / KIP, k = i % KIP;
    float v = (k < BFD && n < H) ? Wi[k*H + n] : 0.f;
    Wt[i] = (bf16)v;
}
__global__ void k_prep_wh(const float* __restrict__ Wh, bf16* __restrict__ Wt){ // [HP][HP]
    int i = blockIdx.x*256 + threadIdx.x; if (i >= HP*HP) return;
    int n = i / HP, k = i % HP;
    float v = (k < H && n < H) ? Wh[k*H + n] : 0.f;
    Wt[i] = (bf16)v;
}
__global__ void k_prep_wo(const float* __restrict__ Wo, bf16* __restrict__ Wt){ // [HP][KO]
    int i = blockIdx.x*256 + threadIdx.x; if (i >= HP*KO) return;
    int n = i / KO, k = i % KO;
    float v = 0.f;
    if (n < H) {
        if (k < AF)                       v = Wo[k*H + n];
        else if (k >= AOFF && k < AOFF+H) v = Wo[(k - AOFF + AF)*H + n];
    }
    Wt[i] = (bf16)v;
}
// cat [NA][KO]: cols 0..135 <- f_atoms (133 real + 3 zero), cols 440..447 <- 0
__global__ void k_init_cat(const float* __restrict__ fa, bf16* __restrict__ cat){
    long u = (long)blockIdx.x*256 + threadIdx.x; if (u >= (long)NA*18) return;
    int c = (int)(u % 18); long a = u / 18;
    bf16x8 v;
    if (c < 17) {
        int c0 = c*8;
        #pragma unroll
        for (int j=0;j<8;j++){
            int col = c0 + j;
            float f = (col < AF) ? fa[a*AF + col] : 0.f;
            v[j] = (bf16)f;
        }
        *(bf16x8*)(cat + a*KO + c0) = v;
    } else {
        #pragma unroll
        for (int j=0;j<8;j++) v[j] = (bf16)0.f;
        *(bf16x8*)(cat + a*KO + 440) = v;
    }
}

// ---- gather: out[a] = sum_k w_bonds[a2b[a,k]] * relu(msgraw[a2b[a,k]]) ----
__global__ void k_gather_amsg(const bf16* __restrict__ msg, const int* __restrict__ a2b,
                              const float* __restrict__ w_bonds,
                              bf16* __restrict__ out, int out_stride, int col_off, int nchunks){
    long u = (long)blockIdx.x*256 + threadIdx.x;
    if (u >= (long)NA*nchunks) return;
    int c = (int)(u % nchunks); long a = u / nchunks;
    int c0 = c*8;
    float acc[8] = {0,0,0,0,0,0,0,0};
    #pragma unroll
    for (int k=0;k<MAX_NB;k++){
        int b = a2b[a*MAX_NB + k];
        float w = w_bonds[b];
        bf16x8 m = *(const bf16x8*)(msg + (long)b*HP + c0);
        #pragma unroll
        for (int j=0;j<8;j++) acc[j] += w * fmaxf((float)m[j], 0.f);
    }
    bf16x8 o;
    #pragma unroll
    for (int j=0;j<8;j++) o[j] = (bf16)acc[j];
    *(bf16x8*)(out + (long)a*out_stride + col_off + c0) = o;
}

// ------------- MFMA GEMM: A-only LDS (full K, single barrier), B from L2 -------------
// BM=64 rows/block, BN=320 (full width), 8 waves in 2M x 4N (wave out 32x80).
// MODE 0: A = f_bonds fp32 [M][147], convert+pad on stage     (GEMM1)
// MODE 1: A[b] = amsg[b2a[b]] - relu(msgsrc[b2revb[b]])*w_b   (GEMM2/3, fused bond_pre)
// MODE 2: A = cat bf16 [M][KO] direct; +bias +relu            (GEMM4)
// Bt: [HP][K] bf16 pre-transposed, zero-padded. out: [M][HP] bf16.
template<int MODE, int K>
__global__ __launch_bounds__(512)
void k_gemm(const void* __restrict__ Asrc, const bf16* __restrict__ msgsrc,
            const int* __restrict__ b2a, const int* __restrict__ b2revb,
            const float* __restrict__ w_bonds,
            const bf16* __restrict__ Bt, int M,
            const bf16* __restrict__ add, const float* __restrict__ bias,
            bf16* __restrict__ out)
{
    constexpr int LDTE = K + 24;          // dword stride ≡ 12 (mod 32): reads conflict-free
    __shared__ bf16 As[BM * LDTE];
    const int t = threadIdx.x;
    const int row0 = blockIdx.x * BM;

    // ---------------- A staging: all loads issued up-front, one barrier ----------------
    const int sr = t >> 3;                // 0..63
    const int c8 = (t & 7) * 8;           // chunk base col
    int arow = row0 + sr; if (arow >= M) arow = M - 1;
    constexpr int NJ = K / 64;            // 64-col groups per row-octet

    if (MODE == 0) {
        const float* fb = (const float*)Asrc;
        #pragma unroll
        for (int j = 0; j < NJ; j++) {
            int col = c8 + j*64;
            bf16x8 av;
            #pragma unroll
            for (int jj = 0; jj < 8; jj++) {
                int k = col + jj;
                av[jj] = (bf16)(k < BFD ? fb[(long)arow*BFD + k] : 0.f);
            }
            *(bf16x8*)(&As[sr*LDTE + col]) = av;
        }
    } else if (MODE == 1) {
        const bf16* am = (const bf16*)Asrc;
        const int ia = b2a[arow], ir = b2revb[arow];
        const float w = w_bonds[arow];
        bf16x8 a8[NJ], m8[NJ];
        #pragma unroll
        for (int j = 0; j < NJ; j++) {
            a8[j] = *(const bf16x8*)(am     + (long)ia*HP + c8 + j*64);
            m8[j] = *(const bf16x8*)(msgsrc + (long)ir*HP + c8 + j*64);
        }
        #pragma unroll
        for (int j = 0; j < NJ; j++) {
            bf16x8 av;
            #pragma unroll
            for (int jj = 0; jj < 8; jj++)
                av[jj] = (bf16)((float)a8[j][jj] - fmaxf((float)m8[j][jj], 0.f) * w);
            *(bf16x8*)(&As[sr*LDTE + c8 + j*64]) = av;
        }
    } else {
        const bf16* am = (const bf16*)Asrc;
        #pragma unroll
        for (int j = 0; j < NJ; j++) {
            bf16x8 av = *(const bf16x8*)(am + (long)arow*KO + c8 + j*64);
            *(bf16x8*)(&As[sr*LDTE + c8 + j*64]) = av;
        }
    }
    __syncthreads();

    // ---------------- compute: 2M x 4N waves, B-fragments straight from L2 ----------------
    const int wave = t >> 6, lane = t & 63;
    const int wm = wave >> 2, wn = wave & 3;
    const int kr = lane >> 4, lr = lane & 15;
    f32x4 acc[2][5] = {};

    #pragma unroll
    for (int kk = 0; kk < K; kk += 32) {
        bf16x8 af[2], bfr[5];
        #pragma unroll
        for (int m = 0; m < 2; m++)
            af[m] = *(const bf16x8*)(&As[(wm*32 + m*16 + lr)*LDTE + kk + kr*8]);
        #pragma unroll
        for (int n = 0; n < 5; n++)
            bfr[n] = *(const bf16x8*)(Bt + (long)(wn*80 + n*16 + lr)*K + kk + kr*8);
        #pragma unroll
        for (int m = 0; m < 2; m++)
            #pragma unroll
            for (int n = 0; n < 5; n++)
                acc[m][n] = __builtin_amdgcn_mfma_f32_16x16x32_bf16(af[m], bfr[n], acc[m][n], 0, 0, 0);
    }

    #pragma unroll
    for (int m = 0; m < 2; m++)
    #pragma unroll
    for (int n = 0; n < 5; n++)
    #pragma unroll
    for (int r = 0; r < 4; r++) {
        int row = row0 + wm*32 + m*16 + kr*4 + r;
        if (row >= M) continue;
        int col = wn*80 + n*16 + lr;
        float v = acc[m][n][r];
        if (add)  v += (float)add[(long)row*HP + col];
        if (bias) v += (col < H) ? bias[col] : 0.f;
        if (MODE == 2) v = fmaxf(v, 0.f);
        out[(long)row*HP + col] = (bf16)v;
    }
}

// ---------------- per-molecule weighted mean ----------------
__global__ void k_seg(const bf16* __restrict__ ah, const float* __restrict__ w_atoms,
                      const float* __restrict__ dop, float* __restrict__ out){
    int m = blockIdx.x; int t = threadIdx.x;
    __shared__ float ws_sum;
    float w = 0.f;
    if (t < APM) w = w_atoms[1 + m*APM + t];
    if (t < 64) {
        for (int o=32;o;o>>=1) w += __shfl_down(w, o);
        if (t==0) ws_sum = w;
    }
    __syncthreads();
    float scale = dop[m] / ws_sum;
    for (int h = t; h < H; h += 256) {
        float acc = 0.f;
        for (int j=0;j<APM;j++){
            int a = 1 + m*APM + j;
            acc += (float)ah[(long)a*HP + h] * w_atoms[a];
        }
        out[m*H + h] = acc * scale;
    }
}

__global__ void k_zero(float* __restrict__ out, int n){
    int i = blockIdx.x*256 + threadIdx.x;
    if (i < n) out[i] = 0.f;
}

extern "C" void kernel_launch(void* const* d_in, const int* in_sizes, int n_in,
                              void* d_out, int out_size, void* d_ws, size_t ws_size,
                              hipStream_t stream) {
    const float* f_atoms = (const float*)d_in[0];
    const float* f_bonds = (const float*)d_in[1];
    const float* w_atoms = (const float*)d_in[2];
    const float* w_bonds = (const float*)d_in[3];
    const float* dop     = (const float*)d_in[4];
    const float* W_i     = (const float*)d_in[5];
    const float* W_h     = (const float*)d_in[6];
    const float* W_o     = (const float*)d_in[7];
    const float* b_o     = (const float*)d_in[8];
    const int*   a2b     = (const int*)d_in[9];
    const int*   b2a     = (const int*)d_in[10];
    const int*   b2revb  = (const int*)d_in[11];
    float* out = (float*)d_out;
    (void)in_sizes; (void)n_in;

    const size_t R_BIG = ((size_t)NB*HP*2 + 255) & ~(size_t)255;   // 128 MB
    const size_t R_ATM = ((size_t)NA*HP*2 + 255) & ~(size_t)255;   //  64 MB
    const size_t R_WI  = ((size_t)HP*KIP*2 + 255) & ~(size_t)255;
    const size_t R_WH  = ((size_t)HP*HP*2 + 255) & ~(size_t)255;
    const size_t R_WO  = ((size_t)HP*KO*2 + 255) & ~(size_t)255;
    const size_t need  = 3*R_BIG + R_ATM + R_WI + R_WH + R_WO;

    if (ws_size < need) {
        k_zero<<<(out_size+255)/256, 256, 0, stream>>>(out, out_size);
        return;
    }

    char* ws = (char*)d_ws;
    bf16* inp  = (bf16*)ws;                    // GEMM1 out (raw), live to end of GEMM3
    bf16* msgA = (bf16*)(ws + R_BIG);          // GEMM2 out (raw); later aliased by cat
    bf16* msgB = (bf16*)(ws + 2*R_BIG);        // GEMM3 out (raw)
    bf16* amsg = (bf16*)(ws + 3*R_BIG);        // neighbor sums; later aliased by ah
    bf16* wit  = (bf16*)(ws + 3*R_BIG + R_ATM);
    bf16* wht  = (bf16*)((char*)wit + R_WI);
    bf16* wot  = (bf16*)((char*)wht + R_WH);
    bf16* cat  = msgA;                         // alias: msgA dead after GEMM3
    bf16* ah   = amsg;                         // alias: amsg dead after GEMM3

    k_prep_wi<<<(HP*KIP+255)/256, 256, 0, stream>>>(W_i, wit);
    k_prep_wh<<<(HP*HP+255)/256, 256, 0, stream>>>(W_h, wht);
    k_prep_wo<<<(HP*KO+255)/256, 256, 0, stream>>>(W_o, wot);

    const int GB = (NB + BM - 1) / BM;   // 3126
    const int GA = (NA + BM - 1) / BM;   // 1563

    // inp = f_bonds @ W_i   (raw; relu applied on every read)
    k_gemm<0, KIP><<<GB, 512, 0, stream>>>(f_bonds, nullptr, nullptr, nullptr, nullptr,
                                           wit, NB, nullptr, nullptr, inp);
    // depth 1
    k_gather_amsg<<<(int)(((long)NA*40+255)/256), 256, 0, stream>>>(
        inp, a2b, w_bonds, amsg, HP, 0, 40);
    k_gemm<1, HP><<<GB, 512, 0, stream>>>(amsg, inp, b2a, b2revb, w_bonds,
                                          wht, NB, inp, nullptr, msgA);
    // depth 2
    k_gather_amsg<<<(int)(((long)NA*40+255)/256), 256, 0, stream>>>(
        msgA, a2b, w_bonds, amsg, HP, 0, 40);
    k_gemm<1, HP><<<GB, 512, 0, stream>>>(amsg, msgA, b2a, b2revb, w_bonds,
                                          wht, NB, inp, nullptr, msgB);
    // readout
    k_init_cat<<<(int)(((long)NA*18+255)/256), 256, 0, stream>>>(f_atoms, cat);
    k_gather_amsg<<<(int)(((long)NA*38+255)/256), 256, 0, stream>>>(
        msgB, a2b, w_bonds, cat, KO, AOFF, 38);
    k_gemm<2, KO><<<GA, 512, 0, stream>>>(cat, nullptr, nullptr, nullptr, nullptr,
                                          wot, NA, nullptr, b_o, ah);
    k_seg<<<NUM_MOLS, 256, 0, stream>>>(ah, w_atoms, dop, out);
}

// Round 5
// 802.992 us; speedup vs baseline: 1.3375x; 1.3375x over previous
//
#include <hip/hip_runtime.h>

typedef __bf16 bf16;
typedef bf16 bf16x8 __attribute__((ext_vector_type(8)));
typedef float f32x4 __attribute__((ext_vector_type(4)));

#define NUM_MOLS 2000
#define APM 50
#define NA (NUM_MOLS*APM+1)      // 100001
#define NB (2*NUM_MOLS*APM+1)    // 200001
#define MAX_NB 6
#define AF 133
#define BFD 147
#define H 300
#define HP 320
#define KIP 192                  // padded BOND_FDIM (3 x 64)
#define KO 448                   // padded concat dim: 133 + 3 pad + 300 + 12 pad
#define AOFF 136                 // a_message column offset inside cat
#define BM 64
#define LDTE 72                  // LDS row stride (144 B, 16B-aligned; reads 2-way = free)

// ---------------- weight prep (pad + transpose to [N][K] bf16) ----------------
__global__ void k_prep_wi(const float* __restrict__ Wi, bf16* __restrict__ Wt){ // [HP][KIP]
    int i = blockIdx.x*256 + threadIdx.x; if (i >= HP*KIP) return;
    int n = i / KIP, k = i % KIP;
    float v = (k < BFD && n < H) ? Wi[k*H + n] : 0.f;
    Wt[i] = (bf16)v;
}
__global__ void k_prep_wh(const float* __restrict__ Wh, bf16* __restrict__ Wt){ // [HP][HP]
    int i = blockIdx.x*256 + threadIdx.x; if (i >= HP*HP) return;
    int n = i / HP, k = i % HP;
    float v = (k < H && n < H) ? Wh[k*H + n] : 0.f;
    Wt[i] = (bf16)v;
}
__global__ void k_prep_wo(const float* __restrict__ Wo, bf16* __restrict__ Wt){ // [HP][KO]
    int i = blockIdx.x*256 + threadIdx.x; if (i >= HP*KO) return;
    int n = i / KO, k = i % KO;
    float v = 0.f;
    if (n < H) {
        if (k < AF)                       v = Wo[k*H + n];
        else if (k >= AOFF && k < AOFF+H) v = Wo[(k - AOFF + AF)*H + n];
    }
    Wt[i] = (bf16)v;
}
// cat [NA][KO]: cols 0..135 <- f_atoms (133 real + 3 zero), cols 440..447 <- 0
__global__ void k_init_cat(const float* __restrict__ fa, bf16* __restrict__ cat){
    long u = (long)blockIdx.x*256 + threadIdx.x; if (u >= (long)NA*18) return;
    int c = (int)(u % 18); long a = u / 18;
    bf16x8 v;
    if (c < 17) {
        int c0 = c*8;
        #pragma unroll
        for (int j=0;j<8;j++){
            int col = c0 + j;
            float f = (col < AF) ? fa[a*AF + col] : 0.f;
            v[j] = (bf16)f;
        }
        *(bf16x8*)(cat + a*KO + c0) = v;
    } else {
        #pragma unroll
        for (int j=0;j<8;j++) v[j] = (bf16)0.f;
        *(bf16x8*)(cat + a*KO + 440) = v;
    }
}

// ---- gather: out[a] = sum_k w_bonds[a2b[a,k]] * relu(msgraw[a2b[a,k]]) ----
__global__ void k_gather_amsg(const bf16* __restrict__ msg, const int* __restrict__ a2b,
                              const float* __restrict__ w_bonds,
                              bf16* __restrict__ out, int out_stride, int col_off, int nchunks){
    long u = (long)blockIdx.x*256 + threadIdx.x;
    if (u >= (long)NA*nchunks) return;
    int c = (int)(u % nchunks); long a = u / nchunks;
    int c0 = c*8;
    float acc[8] = {0,0,0,0,0,0,0,0};
    #pragma unroll
    for (int k=0;k<MAX_NB;k++){
        int b = a2b[a*MAX_NB + k];
        float w = w_bonds[b];
        bf16x8 m = *(const bf16x8*)(msg + (long)b*HP + c0);
        #pragma unroll
        for (int j=0;j<8;j++) acc[j] += w * fmaxf((float)m[j], 0.f);
    }
    bf16x8 o;
    #pragma unroll
    for (int j=0;j<8;j++) o[j] = (bf16)acc[j];
    *(bf16x8*)(out + (long)a*out_stride + col_off + c0) = o;
}

// ---- MFMA GEMM, BM=64 x BN=320(full), BK=64, one-step register prefetch ----
// MODE 0: A = f_bonds fp32 [M][147], convert+pad on stage     (GEMM1)
// MODE 1: A[b] = amsg[b2a[b]] - relu(msgsrc[b2revb[b]])*w_b   (GEMM2/3, fused bond_pre)
// MODE 2: A = cat bf16 [M][KO] direct; +bias +relu            (GEMM4)
// Bt: [HP][K] bf16 pre-transposed, zero-padded. out: [M][HP] bf16.
template<int MODE, int K>
__global__ __launch_bounds__(512)
void k_gemm(const void* __restrict__ Asrc, const bf16* __restrict__ msgsrc,
            const int* __restrict__ b2a, const int* __restrict__ b2revb,
            const float* __restrict__ w_bonds,
            const bf16* __restrict__ Bt, int M,
            const bf16* __restrict__ add, const float* __restrict__ bias,
            bf16* __restrict__ out)
{
    constexpr int NSTEP = K / 64;
    __shared__ bf16 As[BM][LDTE];
    __shared__ bf16 Bs[HP][LDTE];
    const int t = threadIdx.x;
    const int row0 = blockIdx.x * BM;

    const int sr = t >> 3;            // A staging row 0..63
    const int sc = (t & 7) * 8;       // staging col chunk
    int arow = row0 + sr; if (arow >= M) arow = M - 1;
    int ia = 0, ir = 0; float w = 0.f;
    if (MODE == 1) { ia = b2a[arow]; ir = b2revb[arow]; w = w_bonds[arow]; }

    // register staging (filled by issue(), drained by commit())
    float  fa8[8];
    bf16x8 ra, rm;
    bf16x8 rb[5];

    auto issue = [&](int k0){
        if constexpr (MODE == 0) {
            const float* fb = (const float*)Asrc;
            #pragma unroll
            for (int j = 0; j < 8; j++) {
                int k = k0 + sc + j;
                fa8[j] = (k < BFD) ? fb[(long)arow*BFD + k] : 0.f;
            }
        } else if constexpr (MODE == 1) {
            ra = *(const bf16x8*)((const bf16*)Asrc + (long)ia*HP + k0 + sc);
            rm = *(const bf16x8*)(msgsrc            + (long)ir*HP + k0 + sc);
        } else {
            ra = *(const bf16x8*)((const bf16*)Asrc + (long)arow*KO + k0 + sc);
        }
        #pragma unroll
        for (int i = 0; i < 5; i++) {
            int c = t + 512*i;
            rb[i] = *(const bf16x8*)(Bt + (long)(c >> 3)*K + k0 + (c & 7)*8);
        }
    };
    auto commit = [&](){
        bf16x8 av;
        if constexpr (MODE == 0) {
            #pragma unroll
            for (int j = 0; j < 8; j++) av[j] = (bf16)fa8[j];
        } else if constexpr (MODE == 1) {
            #pragma unroll
            for (int j = 0; j < 8; j++)
                av[j] = (bf16)((float)ra[j] - fmaxf((float)rm[j], 0.f) * w);
        } else {
            av = ra;
        }
        *(bf16x8*)(&As[sr][sc]) = av;
        #pragma unroll
        for (int i = 0; i < 5; i++) {
            int c = t + 512*i;
            *(bf16x8*)(&Bs[c >> 3][(c & 7)*8]) = rb[i];
        }
    };

    const int wave = t >> 6, lane = t & 63;
    const int wm = wave >> 2, wn = wave & 3;      // 2M x 4N wave grid
    const int kr = lane >> 4, lr = lane & 15;
    f32x4 acc[2][5] = {};

    issue(0); commit();
    __syncthreads();

    #pragma unroll
    for (int s = 0; s < NSTEP; s++) {
        if (s + 1 < NSTEP) issue((s + 1) * 64);   // prefetch next step BEFORE compute
        #pragma unroll
        for (int kk = 0; kk < 64; kk += 32) {
            bf16x8 af[2], bfr[5];
            #pragma unroll
            for (int m = 0; m < 2; m++)
                af[m] = *(const bf16x8*)(&As[wm*32 + m*16 + lr][kk + kr*8]);
            #pragma unroll
            for (int n = 0; n < 5; n++)
                bfr[n] = *(const bf16x8*)(&Bs[wn*80 + n*16 + lr][kk + kr*8]);
            #pragma unroll
            for (int m = 0; m < 2; m++)
                #pragma unroll
                for (int n = 0; n < 5; n++)
                    acc[m][n] = __builtin_amdgcn_mfma_f32_16x16x32_bf16(af[m], bfr[n], acc[m][n], 0, 0, 0);
        }
        if (s + 1 < NSTEP) {
            __syncthreads();      // all compute reads of this step done
            commit();             // vmcnt wait lands here, after a full compute phase
            __syncthreads();      // writes visible
        }
    }

    #pragma unroll
    for (int m = 0; m < 2; m++)
    #pragma unroll
    for (int n = 0; n < 5; n++)
    #pragma unroll
    for (int r = 0; r < 4; r++) {
        int row = row0 + wm*32 + m*16 + kr*4 + r;
        if (row >= M) continue;
        int col = wn*80 + n*16 + lr;
        float v = acc[m][n][r];
        if (add)  v += (float)add[(long)row*HP + col];
        if (bias) v += (col < H) ? bias[col] : 0.f;
        if (MODE == 2) v = fmaxf(v, 0.f);
        out[(long)row*HP + col] = (bf16)v;
    }
}

// ---------------- per-molecule weighted mean ----------------
__global__ void k_seg(const bf16* __restrict__ ah, const float* __restrict__ w_atoms,
                      const float* __restrict__ dop, float* __restrict__ out){
    int m = blockIdx.x; int t = threadIdx.x;
    __shared__ float ws_sum;
    float w = 0.f;
    if (t < APM) w = w_atoms[1 + m*APM + t];
    if (t < 64) {
        for (int o=32;o;o>>=1) w += __shfl_down(w, o);
        if (t==0) ws_sum = w;
    }
    __syncthreads();
    float scale = dop[m] / ws_sum;
    for (int h = t; h < H; h += 256) {
        float acc = 0.f;
        for (int j=0;j<APM;j++){
            int a = 1 + m*APM + j;
            acc += (float)ah[(long)a*HP + h] * w_atoms[a];
        }
        out[m*H + h] = acc * scale;
    }
}

__global__ void k_zero(float* __restrict__ out, int n){
    int i = blockIdx.x*256 + threadIdx.x;
    if (i < n) out[i] = 0.f;
}

extern "C" void kernel_launch(void* const* d_in, const int* in_sizes, int n_in,
                              void* d_out, int out_size, void* d_ws, size_t ws_size,
                              hipStream_t stream) {
    const float* f_atoms = (const float*)d_in[0];
    const float* f_bonds = (const float*)d_in[1];
    const float* w_atoms = (const float*)d_in[2];
    const float* w_bonds = (const float*)d_in[3];
    const float* dop     = (const float*)d_in[4];
    const float* W_i     = (const float*)d_in[5];
    const float* W_h     = (const float*)d_in[6];
    const float* W_o     = (const float*)d_in[7];
    const float* b_o     = (const float*)d_in[8];
    const int*   a2b     = (const int*)d_in[9];
    const int*   b2a     = (const int*)d_in[10];
    const int*   b2revb  = (const int*)d_in[11];
    float* out = (float*)d_out;
    (void)in_sizes; (void)n_in;

    const size_t R_BIG = ((size_t)NB*HP*2 + 255) & ~(size_t)255;   // 128 MB
    const size_t R_ATM = ((size_t)NA*HP*2 + 255) & ~(size_t)255;   //  64 MB
    const size_t R_WI  = ((size_t)HP*KIP*2 + 255) & ~(size_t)255;
    const size_t R_WH  = ((size_t)HP*HP*2 + 255) & ~(size_t)255;
    const size_t R_WO  = ((size_t)HP*KO*2 + 255) & ~(size_t)255;
    const size_t need  = 3*R_BIG + R_ATM + R_WI + R_WH + R_WO;

    if (ws_size < need) {
        k_zero<<<(out_size+255)/256, 256, 0, stream>>>(out, out_size);
        return;
    }

    char* ws = (char*)d_ws;
    bf16* inp  = (bf16*)ws;                    // GEMM1 out (raw), live to end of GEMM3
    bf16* msgA = (bf16*)(ws + R_BIG);          // GEMM2 out (raw); later aliased by cat
    bf16* msgB = (bf16*)(ws + 2*R_BIG);        // GEMM3 out (raw)
    bf16* amsg = (bf16*)(ws + 3*R_BIG);        // neighbor sums; later aliased by ah
    bf16* wit  = (bf16*)(ws + 3*R_BIG + R_ATM);
    bf16* wht  = (bf16*)((char*)wit + R_WI);
    bf16* wot  = (bf16*)((char*)wht + R_WH);
    bf16* cat  = msgA;                         // alias: msgA dead after GEMM3
    bf16* ah   = amsg;                         // alias: amsg dead after GEMM3

    k_prep_wi<<<(HP*KIP+255)/256, 256, 0, stream>>>(W_i, wit);
    k_prep_wh<<<(HP*HP+255)/256, 256, 0, stream>>>(W_h, wht);
    k_prep_wo<<<(HP*KO+255)/256, 256, 0, stream>>>(W_o, wot);

    const int GB = (NB + BM - 1) / BM;   // 3126
    const int GA = (NA + BM - 1) / BM;   // 1563

    // inp = f_bonds @ W_i   (raw; relu applied on every read)
    k_gemm<0, KIP><<<GB, 512, 0, stream>>>(f_bonds, nullptr, nullptr, nullptr, nullptr,
                                           wit, NB, nullptr, nullptr, inp);
    // depth 1
    k_gather_amsg<<<(int)(((long)NA*40+255)/256), 256, 0, stream>>>(
        inp, a2b, w_bonds, amsg, HP, 0, 40);
    k_gemm<1, HP><<<GB, 512, 0, stream>>>(amsg, inp, b2a, b2revb, w_bonds,
                                          wht, NB, inp, nullptr, msgA);
    // depth 2
    k_gather_amsg<<<(int)(((long)NA*40+255)/256), 256, 0, stream>>>(
        msgA, a2b, w_bonds, amsg, HP, 0, 40);
    k_gemm<1, HP><<<GB, 512, 0, stream>>>(amsg, msgA, b2a, b2revb, w_bonds,
                                          wht, NB, inp, nullptr, msgB);
    // readout
    k_init_cat<<<(int)(((long)NA*18+255)/256), 256, 0, stream>>>(f_atoms, cat);
    k_gather_amsg<<<(int)(((long)NA*38+255)/256), 256, 0, stream>>>(
        msgB, a2b, w_bonds, cat, KO, AOFF, 38);
    k_gemm<2, KO><<<GA, 512, 0, stream>>>(cat, nullptr, nullptr, nullptr, nullptr,
                                          wot, NA, nullptr, b_o, ah);
    k_seg<<<NUM_MOLS, 256, 0, stream>>>(ah, w_atoms, dop, out);
}